// Round 9
// baseline (190.885 us; speedup 1.0000x reference)
//
#include <hip/hip_runtime.h>
#include <hip/hip_bf16.h>
#include <math.h>

#define B_ 2
#define T_ 2048
#define C_ 1024
#define H_ 16
#define HKV_ 4
#define G_ 4
#define HD_ 64
#define KVC_ 256      // HKV*HD
#define NQKV_ 1536    // C_ + 2*KVC_
#define NQT_ 32       // T_/64 q-tiles

typedef __attribute__((ext_vector_type(8))) short bf16x8;
typedef __attribute__((ext_vector_type(4))) short bf16x4;
typedef __attribute__((ext_vector_type(4))) float f32x4;

static __device__ inline short f2bf(float f) {          // RNE (epilogues)
    __hip_bfloat16 h = __float2bfloat16(f);
    short s;
    __builtin_memcpy(&s, &h, 2);
    return s;
}
static __device__ inline float bf2f(short s) {
    unsigned int u = ((unsigned int)(unsigned short)s) << 16;
    float f;
    __builtin_memcpy(&f, &u, 4);
    return f;
}
// pack 4 fp32 -> bf16x4 by truncation (hot path; consistent num/denom)
static __device__ inline bf16x4 pack4_trunc(float p0, float p1, float p2, float p3) {
    unsigned a, b, c, d;
    __builtin_memcpy(&a, &p0, 4); __builtin_memcpy(&b, &p1, 4);
    __builtin_memcpy(&c, &p2, 4); __builtin_memcpy(&d, &p3, 4);
    int2 v;
    v.x = (int)((a >> 16) | (b & 0xffff0000u));
    v.y = (int)((c >> 16) | (d & 0xffff0000u));
    return __builtin_bit_cast(bf16x4, v);
}

static __device__ inline f32x4 mfma32(bf16x8 a, bf16x8 b, f32x4 c) {
    return __builtin_amdgcn_mfma_f32_16x16x32_bf16(a, b, c, 0, 0, 0);
}
static __device__ inline f32x4 mfma16(bf16x4 a, bf16x4 b, f32x4 c) {
    return __builtin_amdgcn_mfma_f32_16x16x16bf16_1k(a, b, c, 0, 0, 0);
}

// async global->LDS, 16B per lane; lds base wave-uniform, dest = base + lane*16.
static __device__ inline void gload_lds16(const short* g, short* lds) {
    __builtin_amdgcn_global_load_lds(
        (const __attribute__((address_space(1))) unsigned int*)g,
        (__attribute__((address_space(3))) unsigned int*)lds, 16, 0, 0);
}

// ---------------- elementwise fp32 -> bf16 cast (8 elems/thread) ----------
__global__ __launch_bounds__(256) void cast_bf16(
    const float* __restrict__ in, short* __restrict__ out, int n)
{
    const int i = (blockIdx.x * 256 + threadIdx.x) * 8;
    if (i >= n) return;
    const float4 a = *(const float4*)(in + i);
    const float4 b = *(const float4*)(in + i + 4);
    bf16x8 o;
    o[0] = f2bf(a.x); o[1] = f2bf(a.y); o[2] = f2bf(a.z); o[3] = f2bf(a.w);
    o[4] = f2bf(b.x); o[5] = f2bf(b.y); o[6] = f2bf(b.z); o[7] = f2bf(b.w);
    *(bf16x8*)(out + i) = o;
}

// ------------- fused weight transpose+cast (z selects matrix) -------------
__global__ __launch_bounds__(256) void w_transpose(
    const float* __restrict__ Wq, const float* __restrict__ Wk,
    const float* __restrict__ Wv, const float* __restrict__ Wo,
    short* __restrict__ Wt, short* __restrict__ Wot)
{
    const int z = blockIdx.z;
    const float* in;
    short* out;
    int N;
    if (z == 0)      { in = Wq; out = Wt;                     N = C_; }
    else if (z == 1) { in = Wk; out = Wt + C_ * C_;           N = KVC_; }
    else if (z == 2) { in = Wv; out = Wt + (C_ + KVC_) * C_;  N = KVC_; }
    else             { in = Wo; out = Wot;                    N = C_; }
    const int n0 = blockIdx.x * 32;
    if (n0 >= N) return;
    __shared__ float t[32][33];
    const int tx = threadIdx.x, ty = threadIdx.y;     // 32 x 8
    const int k0 = blockIdx.y * 32;
    #pragma unroll
    for (int j = 0; j < 4; j++)
        t[ty + j * 8][tx] = in[(size_t)(k0 + ty + j * 8) * N + n0 + tx];
    __syncthreads();
    #pragma unroll
    for (int j = 0; j < 4; j++)
        out[(size_t)(n0 + ty + j * 8) * C_ + k0 + tx] = f2bf(t[tx][ty + j * 8]);
}

// ---------------- bf16 MFMA GEMM: 64x128 tile, BK=32 ----------------------
// MODE 0: fp32 plain output.  MODE 1: fused QKV epilogue — Q cols -> bf16
// QKV buffer; K cols -> swizzled Ktg tiles; V cols -> transposed Vtg tiles
// (kv_tile prepass eliminated; V transpose is free in C-layout: reg r spans
// consecutive rows=keys -> b64 stores).
template <int MODE>
__global__ __launch_bounds__(256) void gemm_bf16(
    const short* __restrict__ A, const short* __restrict__ Bt,
    void* __restrict__ Cout, short* __restrict__ Ktg, short* __restrict__ Vtg,
    int M, int N, int K)
{
    __shared__ short As[64 * 32];
    __shared__ short Bs[128 * 32];
    const int tid = threadIdx.x;
    const int wave = tid >> 6, lane = tid & 63;
    const int l15 = lane & 15, quad = lane >> 4;
    const int row0 = blockIdx.y * 64, col0 = blockIdx.x * 128;
    const int wrow = (wave >> 1) * 32, wcol = (wave & 1) * 64;

    f32x4 acc[2][4];
    #pragma unroll
    for (int i = 0; i < 2; i++)
        #pragma unroll
        for (int j = 0; j < 4; j++)
            acc[i][j] = (f32x4){0.f, 0.f, 0.f, 0.f};

    for (int kt = 0; kt < K; kt += 32) {
        __syncthreads();
        {
            const int r = wave * 16 + (lane >> 2);
            const int kof = (lane & 3) * 8;
            gload_lds16(A + (size_t)(row0 + r) * K + kt + kof, &As[wave * 512]);
        }
        #pragma unroll
        for (int c2 = 0; c2 < 2; c2++) {
            const int c = wave * 2 + c2;
            const int r = c * 16 + (lane >> 2);
            const int kof = (lane & 3) * 8;
            gload_lds16(Bt + (size_t)(col0 + r) * K + kt + kof, &Bs[c * 512]);
        }
        __syncthreads();

        bf16x8 af[2], bf[4];
        #pragma unroll
        for (int mt = 0; mt < 2; mt++)
            af[mt] = *(const bf16x8*)&As[(wrow + mt * 16 + l15) * 32 + quad * 8];
        #pragma unroll
        for (int nt = 0; nt < 4; nt++)
            bf[nt] = *(const bf16x8*)&Bs[(wcol + nt * 16 + l15) * 32 + quad * 8];
        #pragma unroll
        for (int mt = 0; mt < 2; mt++)
            #pragma unroll
            for (int nt = 0; nt < 4; nt++)
                acc[mt][nt] = mfma32(af[mt], bf[nt], acc[mt][nt]);
    }

    if (MODE == 0) {
        #pragma unroll
        for (int mt = 0; mt < 2; mt++)
            #pragma unroll
            for (int r = 0; r < 4; r++) {
                const size_t row = row0 + wrow + mt * 16 + quad * 4 + r;
                #pragma unroll
                for (int nt = 0; nt < 4; nt++)
                    ((float*)Cout)[row * N + col0 + wcol + nt * 16 + l15]
                        = acc[mt][nt][r];
            }
    } else {
        if (col0 < C_) {                    // ---- Q: plain bf16 to QKV ----
            #pragma unroll
            for (int mt = 0; mt < 2; mt++)
                #pragma unroll
                for (int r = 0; r < 4; r++) {
                    const size_t row = row0 + wrow + mt * 16 + quad * 4 + r;
                    #pragma unroll
                    for (int nt = 0; nt < 4; nt++)
                        ((short*)Cout)[row * N + col0 + wcol + nt * 16 + l15]
                            = f2bf(acc[mt][nt][r]);
                }
        } else if (col0 < C_ + KVC_) {      // ---- K: swizzled Ktg tile ----
            const int kh = ((col0 - C_) >> 6) + (wcol >> 6);
            const int b = row0 >> 11, jt = (row0 & (T_ - 1)) >> 6;
            const size_t tbase = (size_t)((b * HKV_ + kh) * 32 + jt) * 4096;
            #pragma unroll
            for (int mt = 0; mt < 2; mt++)
                #pragma unroll
                for (int r = 0; r < 4; r++) {
                    const int key = wrow + mt * 16 + quad * 4 + r;
                    #pragma unroll
                    for (int nt = 0; nt < 4; nt++) {
                        const int d = nt * 16 + l15;
                        Ktg[tbase + key * 64 + (((d >> 3) ^ (key & 7)) << 3) + (d & 7)]
                            = f2bf(acc[mt][nt][r]);
                    }
                }
        } else {                            // ---- V: transposed Vtg tile ----
            const int kh = ((col0 - C_ - KVC_) >> 6) + (wcol >> 6);
            const int b = row0 >> 11, jt = (row0 & (T_ - 1)) >> 6;
            const size_t tbase = (size_t)((b * HKV_ + kh) * 32 + jt) * 4096;
            #pragma unroll
            for (int mt = 0; mt < 2; mt++) {
                const int kblk = ((wrow + mt * 16) >> 3) + (quad >> 1);
                #pragma unroll
                for (int nt = 0; nt < 4; nt++) {
                    const int d = nt * 16 + l15;
                    bf16x4 v4;
                    v4[0] = f2bf(acc[mt][nt][0]); v4[1] = f2bf(acc[mt][nt][1]);
                    v4[2] = f2bf(acc[mt][nt][2]); v4[3] = f2bf(acc[mt][nt][3]);
                    *(bf16x4*)(Vtg + tbase + d * 64
                               + ((kblk ^ (d & 7)) << 3) + ((quad & 1) << 2)) = v4;
                }
            }
        }
    }
}

// ---------------- MFMA flash attention, P-in-registers --------------------
// Block (qx,bh): Q-tiles qtL=qx, qtH=31-qx (constant 33 tile-iters).
// S^T = K·Q^T (kf as A, qf as B — same fragments as before, args swapped):
// C-layout of S^T (col=q, rows=key quad*4+r) IS the B-layout of the K=16
// MFMA, so P^T = exp2(S^T+bias) stays in registers: no P LDS round-trip.
// PV: O^T = V^T·P^T via mfma 16x16x16 (V^T frags = b64 LDS reads, shared by
// both pair-halves). l = ones·P^T. ALiBi folded into MFMA acc-init;
// mask ⟺ bias>0 on the (uniform) diagonal iteration.
__global__ __launch_bounds__(256) void attn_mfma(
    const short* __restrict__ QKV, const short* __restrict__ Ktg,
    const short* __restrict__ Vtg, short* __restrict__ Y)
{
    const int qx = blockIdx.x;                 // 0..15
    const int bh = blockIdx.y;
    const int qtL = qx, qtH = NQT_ - 1 - qx;   // pair sums to 31
    const int b = bh >> 4, h = bh & 15, kh = h >> 2;
    const float slope2 = exp2f(-0.5f * (float)(kh + 1)) * 1.44269504f;
    const int tid = threadIdx.x;
    const int wave = tid >> 6, lane = tid & 63;
    const int l15 = lane & 15, quad = lane >> 4;
    const int lswz = (l15 & 7) * 8;            // K frag-read XOR (shorts)

    __shared__ short Ks[4096];                 // [key][dblk^(key&7)][8]
    __shared__ short Vs[4096];                 // [d][kblk^(d&7)][8]

    const size_t bT = (size_t)b * T_;
    const size_t tb0 = (size_t)((b * HKV_ + kh) * 32) * 4096;
    const int qrow0H = qtH * 64 + wave * 16;   // this wave's 16 H q-rows
    const int qrow0L = qtL * 64 + wave * 16;

    // Q fragments as B-operand (identical bits to A-layout): scale folded in
    const float qscale = 0.125f * 1.44269504f;
    bf16x8 qfH[2], qfL[2];
    #pragma unroll
    for (int k0 = 0; k0 < 2; k0++) {
        const short* qpH = QKV + (bT + qrow0H + l15) * NQKV_ + h * 64;
        const short* qpL = QKV + (bT + qrow0L + l15) * NQKV_ + h * 64;
        bf16x8 rH = *(const bf16x8*)(qpH + k0 * 32 + quad * 8);
        bf16x8 rL = *(const bf16x8*)(qpL + k0 * 32 + quad * 8);
        #pragma unroll
        for (int j = 0; j < 8; j++) {
            qfH[k0][j] = f2bf(bf2f(rH[j]) * qscale);
            qfL[k0][j] = f2bf(bf2f(rL[j]) * qscale);
        }
    }

    // ALiBi bias bases: bias(jtk=0) per (mtk, r); advance by step*jtk
    const float step = slope2 * 64.f;
    f32x4 bBH[4], bBL[4];
    #pragma unroll
    for (int mtk = 0; mtk < 4; mtk++)
        #pragma unroll
        for (int r = 0; r < 4; r++) {
            const int key0 = mtk * 16 + quad * 4 + r;
            bBH[mtk][r] = slope2 * (float)(key0 - wave * 16 - l15 - qtH * 64);
            bBL[mtk][r] = slope2 * (float)(key0 - wave * 16 - l15 - qtL * 64);
        }

    const bf16x4 ones = {(short)0x3F80, (short)0x3F80, (short)0x3F80, (short)0x3F80};

    f32x4 OaccH[4], OaccL[4], laccH, laccL;    // O^T: col=q, row=d
    #pragma unroll
    for (int nt = 0; nt < 4; nt++) {
        OaccH[nt] = (f32x4){0.f, 0.f, 0.f, 0.f};
        OaccL[nt] = (f32x4){0.f, 0.f, 0.f, 0.f};
    }
    laccH = (f32x4){0.f, 0.f, 0.f, 0.f};
    laccL = (f32x4){0.f, 0.f, 0.f, 0.f};

    for (int jtk = 0; jtk <= qtH; jtk++) {
        __syncthreads();                       // prev-tile consumers done
        {
            const short* Ktile = Ktg + tb0 + (size_t)jtk * 4096;
            const short* Vtile = Vtg + tb0 + (size_t)jtk * 4096;
            #pragma unroll
            for (int i = 0; i < 2; i++) {
                const int ch = wave * 2 + i;   // 1KB chunks
                gload_lds16(Ktile + ch * 512 + lane * 8, &Ks[ch * 512]);
                gload_lds16(Vtile + ch * 512 + lane * 8, &Vs[ch * 512]);
            }
        }
        __syncthreads();                       // DMA drained by barrier

        const bool doL = (jtk <= qtL);
        const float jb = step * (float)jtk;

        // K fragments (A-operand), shared by both Q-tiles
        bf16x8 kf[8];
        #pragma unroll
        for (int mtk = 0; mtk < 4; mtk++)
            #pragma unroll
            for (int k0 = 0; k0 < 2; k0++)
                kf[mtk * 2 + k0] = *(const bf16x8*)
                    &Ks[(mtk * 16 + l15) * 64 + (((k0 * 4 + quad) * 8) ^ lswz)];

        // S^T + bias -> P^T in registers; l via ones-MFMA
        bf16x4 pTH[4], pTL[4];
        {
            const bool diag = (jtk == qtH);
            #pragma unroll
            for (int mtk = 0; mtk < 4; mtk++) {
                const f32x4 bias = bBH[mtk] + jb;
                f32x4 a = bias;
                a = mfma32(kf[mtk * 2 + 0], qfH[0], a);
                a = mfma32(kf[mtk * 2 + 1], qfH[1], a);
                float p[4];
                #pragma unroll
                for (int r = 0; r < 4; r++) {
                    p[r] = __builtin_amdgcn_exp2f(a[r]);
                    if (diag && bias[r] > 0.f) p[r] = 0.f;
                }
                pTH[mtk] = pack4_trunc(p[0], p[1], p[2], p[3]);
                laccH = mfma16(ones, pTH[mtk], laccH);
            }
        }
        if (doL) {
            const bool diag = (jtk == qtL);
            #pragma unroll
            for (int mtk = 0; mtk < 4; mtk++) {
                const f32x4 bias = bBL[mtk] + jb;
                f32x4 a = bias;
                a = mfma32(kf[mtk * 2 + 0], qfL[0], a);
                a = mfma32(kf[mtk * 2 + 1], qfL[1], a);
                float p[4];
                #pragma unroll
                for (int r = 0; r < 4; r++) {
                    p[r] = __builtin_amdgcn_exp2f(a[r]);
                    if (diag && bias[r] > 0.f) p[r] = 0.f;
                }
                pTL[mtk] = pack4_trunc(p[0], p[1], p[2], p[3]);
                laccL = mfma16(ones, pTL[mtk], laccL);
            }
        }

        // O^T += V^T · P^T   (V^T A-frags: b64 swizzled reads, shared H/L)
        #pragma unroll
        for (int mtk = 0; mtk < 4; mtk++) {
            const int kblk = (mtk << 1) + (quad >> 1);
            #pragma unroll
            for (int nt = 0; nt < 4; nt++) {
                const bf16x4 vf = *(const bf16x4*)
                    &Vs[(nt * 16 + l15) * 64
                        + ((kblk ^ (l15 & 7)) << 3) + ((quad & 1) << 2)];
                OaccH[nt] = mfma16(vf, pTH[mtk], OaccH[nt]);
                if (doL) OaccL[nt] = mfma16(vf, pTL[mtk], OaccL[nt]);
            }
        }
    }

    // epilogue: O^T col=q(l15), row=d(quad*4+r): 4 consecutive d -> b64 store
    {
        const float invH = 1.f / laccH[0];
        const float invL = 1.f / laccL[0];
        short* ypH = Y + (bT + qrow0H + l15) * C_ + h * 64;
        short* ypL = Y + (bT + qrow0L + l15) * C_ + h * 64;
        #pragma unroll
        for (int nt = 0; nt < 4; nt++) {
            bf16x4 oH, oL;
            #pragma unroll
            for (int r = 0; r < 4; r++) {
                oH[r] = f2bf(OaccH[nt][r] * invH);
                oL[r] = f2bf(OaccL[nt][r] * invL);
            }
            *(bf16x4*)(ypH + nt * 16 + quad * 4) = oH;
            *(bf16x4*)(ypL + nt * 16 + quad * 4) = oL;
        }
    }
}

extern "C" void kernel_launch(void* const* d_in, const int* in_sizes, int n_in,
                              void* d_out, int out_size, void* d_ws, size_t ws_size,
                              hipStream_t stream) {
    const float* x  = (const float*)d_in[0];
    const float* Wq = (const float*)d_in[1];
    const float* Wk = (const float*)d_in[2];
    const float* Wv = (const float*)d_in[3];
    const float* Wo = (const float*)d_in[4];
    float* out = (float*)d_out;

    const int M = B_ * T_;                           // 4096
    short* xb  = (short*)d_ws;                       // [4096][1024]
    short* Wt  = xb  + (size_t)M * C_;               // [1536][1024]
    short* Wot = Wt  + (size_t)NQKV_ * C_;           // [1024][1024]
    short* QKV = Wot + (size_t)C_ * C_;              // [4096][1536] (Q cols only)
    short* Yb  = QKV + (size_t)M * NQKV_;            // [4096][1024]
    short* Ktg = Yb  + (size_t)M * C_;               // [8][32][4096] swizzled
    short* Vtg = Ktg + (size_t)8 * 32 * 4096;        // [8][32][4096] swizzled

    cast_bf16<<<dim3(M * C_ / (256 * 8)), dim3(256), 0, stream>>>(x, xb, M * C_);
    w_transpose<<<dim3(32, 32, 4), dim3(32, 8), 0, stream>>>(Wq, Wk, Wv, Wo, Wt, Wot);

    gemm_bf16<1><<<dim3(NQKV_ / 128, M / 64), dim3(256), 0, stream>>>(
        xb, Wt, QKV, Ktg, Vtg, M, NQKV_, C_);
    attn_mfma<<<dim3(NQT_ / 2, B_ * H_), dim3(256), 0, stream>>>(QKV, Ktg, Vtg, Yb);
    gemm_bf16<0><<<dim3(C_ / 128, M / 64), dim3(256), 0, stream>>>(
        Yb, Wot, out, nullptr, nullptr, M, C_, C_);
}

// Round 10
// 177.231 us; speedup vs baseline: 1.0770x; 1.0770x over previous
//
#include <hip/hip_runtime.h>
#include <hip/hip_bf16.h>
#include <math.h>

#define B_ 2
#define T_ 2048
#define C_ 1024
#define H_ 16
#define HKV_ 4
#define G_ 4
#define HD_ 64
#define KVC_ 256      // HKV*HD
#define NQKV_ 1536    // C_ + 2*KVC_
#define NQT_ 32       // T_/64 q-tiles

typedef __attribute__((ext_vector_type(8))) short bf16x8;
typedef __attribute__((ext_vector_type(4))) short bf16x4;
typedef __attribute__((ext_vector_type(4))) float f32x4;

static __device__ inline short f2bf(float f) {          // RNE (epilogues)
    __hip_bfloat16 h = __float2bfloat16(f);
    short s;
    __builtin_memcpy(&s, &h, 2);
    return s;
}
static __device__ inline float bf2f(short s) {
    unsigned int u = ((unsigned int)(unsigned short)s) << 16;
    float f;
    __builtin_memcpy(&f, &u, 4);
    return f;
}
// pack 4 fp32 -> bf16x4 by truncation (hot path; consistent num/denom)
static __device__ inline bf16x4 pack4_trunc(float p0, float p1, float p2, float p3) {
    unsigned a, b, c, d;
    __builtin_memcpy(&a, &p0, 4); __builtin_memcpy(&b, &p1, 4);
    __builtin_memcpy(&c, &p2, 4); __builtin_memcpy(&d, &p3, 4);
    int2 v;
    v.x = (int)((a >> 16) | (b & 0xffff0000u));
    v.y = (int)((c >> 16) | (d & 0xffff0000u));
    return __builtin_bit_cast(bf16x4, v);
}

static __device__ inline f32x4 mfma32(bf16x8 a, bf16x8 b, f32x4 c) {
    return __builtin_amdgcn_mfma_f32_16x16x32_bf16(a, b, c, 0, 0, 0);
}

// async global->LDS, 16B per lane; lds base wave-uniform, dest = base + lane*16.
static __device__ inline void gload_lds16(const short* g, short* lds) {
    __builtin_amdgcn_global_load_lds(
        (const __attribute__((address_space(1))) unsigned int*)g,
        (__attribute__((address_space(3))) unsigned int*)lds, 16, 0, 0);
}

// ---------------- elementwise fp32 -> bf16 cast (8 elems/thread) ----------
__global__ __launch_bounds__(256) void cast_bf16(
    const float* __restrict__ in, short* __restrict__ out, int n)
{
    const int i = (blockIdx.x * 256 + threadIdx.x) * 8;
    if (i >= n) return;
    const float4 a = *(const float4*)(in + i);
    const float4 b = *(const float4*)(in + i + 4);
    bf16x8 o;
    o[0] = f2bf(a.x); o[1] = f2bf(a.y); o[2] = f2bf(a.z); o[3] = f2bf(a.w);
    o[4] = f2bf(b.x); o[5] = f2bf(b.y); o[6] = f2bf(b.z); o[7] = f2bf(b.w);
    *(bf16x8*)(out + i) = o;
}

// ------------- fused weight transpose+cast (z selects matrix) -------------
__global__ __launch_bounds__(256) void w_transpose(
    const float* __restrict__ Wq, const float* __restrict__ Wk,
    const float* __restrict__ Wv, const float* __restrict__ Wo,
    short* __restrict__ Wt, short* __restrict__ Wot)
{
    const int z = blockIdx.z;
    const float* in;
    short* out;
    int N;
    if (z == 0)      { in = Wq; out = Wt;                     N = C_; }
    else if (z == 1) { in = Wk; out = Wt + C_ * C_;           N = KVC_; }
    else if (z == 2) { in = Wv; out = Wt + (C_ + KVC_) * C_;  N = KVC_; }
    else             { in = Wo; out = Wot;                    N = C_; }
    const int n0 = blockIdx.x * 32;
    if (n0 >= N) return;
    __shared__ float t[32][33];
    const int tx = threadIdx.x, ty = threadIdx.y;     // 32 x 8
    const int k0 = blockIdx.y * 32;
    #pragma unroll
    for (int j = 0; j < 4; j++)
        t[ty + j * 8][tx] = in[(size_t)(k0 + ty + j * 8) * N + n0 + tx];
    __syncthreads();
    #pragma unroll
    for (int j = 0; j < 4; j++)
        out[(size_t)(n0 + ty + j * 8) * C_ + k0 + tx] = f2bf(t[tx][ty + j * 8]);
}

// ---------------- bf16 MFMA GEMM: 64x128 tile, BK=32 ----------------------
// MODE 0: fp32 plain output.  MODE 1: fused QKV epilogue — Q cols -> bf16
// QKV buffer; K cols -> swizzled Ktg tiles; V cols -> transposed Vtg tiles.
template <int MODE>
__global__ __launch_bounds__(256) void gemm_bf16(
    const short* __restrict__ A, const short* __restrict__ Bt,
    void* __restrict__ Cout, short* __restrict__ Ktg, short* __restrict__ Vtg,
    int M, int N, int K)
{
    __shared__ short As[64 * 32];
    __shared__ short Bs[128 * 32];
    const int tid = threadIdx.x;
    const int wave = tid >> 6, lane = tid & 63;
    const int l15 = lane & 15, quad = lane >> 4;
    const int row0 = blockIdx.y * 64, col0 = blockIdx.x * 128;
    const int wrow = (wave >> 1) * 32, wcol = (wave & 1) * 64;

    f32x4 acc[2][4];
    #pragma unroll
    for (int i = 0; i < 2; i++)
        #pragma unroll
        for (int j = 0; j < 4; j++)
            acc[i][j] = (f32x4){0.f, 0.f, 0.f, 0.f};

    for (int kt = 0; kt < K; kt += 32) {
        __syncthreads();
        {
            const int r = wave * 16 + (lane >> 2);
            const int kof = (lane & 3) * 8;
            gload_lds16(A + (size_t)(row0 + r) * K + kt + kof, &As[wave * 512]);
        }
        #pragma unroll
        for (int c2 = 0; c2 < 2; c2++) {
            const int c = wave * 2 + c2;
            const int r = c * 16 + (lane >> 2);
            const int kof = (lane & 3) * 8;
            gload_lds16(Bt + (size_t)(col0 + r) * K + kt + kof, &Bs[c * 512]);
        }
        __syncthreads();

        bf16x8 af[2], bf[4];
        #pragma unroll
        for (int mt = 0; mt < 2; mt++)
            af[mt] = *(const bf16x8*)&As[(wrow + mt * 16 + l15) * 32 + quad * 8];
        #pragma unroll
        for (int nt = 0; nt < 4; nt++)
            bf[nt] = *(const bf16x8*)&Bs[(wcol + nt * 16 + l15) * 32 + quad * 8];
        #pragma unroll
        for (int mt = 0; mt < 2; mt++)
            #pragma unroll
            for (int nt = 0; nt < 4; nt++)
                acc[mt][nt] = mfma32(af[mt], bf[nt], acc[mt][nt]);
    }

    if (MODE == 0) {
        #pragma unroll
        for (int mt = 0; mt < 2; mt++)
            #pragma unroll
            for (int r = 0; r < 4; r++) {
                const size_t row = row0 + wrow + mt * 16 + quad * 4 + r;
                #pragma unroll
                for (int nt = 0; nt < 4; nt++)
                    ((float*)Cout)[row * N + col0 + wcol + nt * 16 + l15]
                        = acc[mt][nt][r];
            }
    } else {
        if (col0 < C_) {                    // ---- Q: plain bf16 to QKV ----
            #pragma unroll
            for (int mt = 0; mt < 2; mt++)
                #pragma unroll
                for (int r = 0; r < 4; r++) {
                    const size_t row = row0 + wrow + mt * 16 + quad * 4 + r;
                    #pragma unroll
                    for (int nt = 0; nt < 4; nt++)
                        ((short*)Cout)[row * N + col0 + wcol + nt * 16 + l15]
                            = f2bf(acc[mt][nt][r]);
                }
        } else if (col0 < C_ + KVC_) {      // ---- K: swizzled Ktg tile ----
            const int kh = ((col0 - C_) >> 6) + (wcol >> 6);
            const int b = row0 >> 11, jt = (row0 & (T_ - 1)) >> 6;
            const size_t tbase = (size_t)((b * HKV_ + kh) * 32 + jt) * 4096;
            #pragma unroll
            for (int mt = 0; mt < 2; mt++)
                #pragma unroll
                for (int r = 0; r < 4; r++) {
                    const int key = wrow + mt * 16 + quad * 4 + r;
                    #pragma unroll
                    for (int nt = 0; nt < 4; nt++) {
                        const int d = nt * 16 + l15;
                        Ktg[tbase + key * 64 + (((d >> 3) ^ (key & 7)) << 3) + (d & 7)]
                            = f2bf(acc[mt][nt][r]);
                    }
                }
        } else {                            // ---- V: transposed Vtg tile ----
            const int kh = ((col0 - C_ - KVC_) >> 6) + (wcol >> 6);
            const int b = row0 >> 11, jt = (row0 & (T_ - 1)) >> 6;
            const size_t tbase = (size_t)((b * HKV_ + kh) * 32 + jt) * 4096;
            #pragma unroll
            for (int mt = 0; mt < 2; mt++) {
                const int kblk = ((wrow + mt * 16) >> 3) + (quad >> 1);
                #pragma unroll
                for (int nt = 0; nt < 4; nt++) {
                    const int d = nt * 16 + l15;
                    bf16x4 v4;
                    v4[0] = f2bf(acc[mt][nt][0]); v4[1] = f2bf(acc[mt][nt][1]);
                    v4[2] = f2bf(acc[mt][nt][2]); v4[3] = f2bf(acc[mt][nt][3]);
                    *(bf16x4*)(Vtg + tbase + d * 64
                               + ((kblk ^ (d & 7)) << 3) + ((quad & 1) << 2)) = v4;
                }
            }
        }
    }
}

// ---------------- MFMA flash attention: S^T + packed-P + K=32 PV ----------
// Block (qx,bh): Q-tiles qtL=qx, qtH=31-qx (constant 33 tile-iters).
// S^T = K·Q^T (kf as A, qf as B): C-layout col=q=l15, row=key=quad*4+r.
// Each thread packs its 4 P values into ONE b64 LDS write at row q=l15
// (P stored [q][key], XOR-swizzled 8-blocks) — vs 16 scalar b16 in R8.
// PV then runs R8's proven K=32 path: pf = 2 b128 reads at row l15,
// vf = 8 shared b128, l via ones-MFMA. ALiBi bias in MFMA acc-init;
// causal mask only on the (uniform) diagonal iter (mask <=> bias>0).
#define LSTR 72

__global__ __launch_bounds__(256) void attn_mfma(
    const short* __restrict__ QKV, const short* __restrict__ Ktg,
    const short* __restrict__ Vtg, short* __restrict__ Y)
{
    const int qx = blockIdx.x;                 // 0..15
    const int bh = blockIdx.y;
    const int qtL = qx, qtH = NQT_ - 1 - qx;   // pair sums to 31
    const int b = bh >> 4, h = bh & 15, kh = h >> 2;
    const float slope2 = exp2f(-0.5f * (float)(kh + 1)) * 1.44269504f;
    const int tid = threadIdx.x;
    const int wave = tid >> 6, lane = tid & 63;
    const int l15 = lane & 15, quad = lane >> 4;
    const int lswz = (l15 & 7) * 8;            // K/V frag-read XOR (shorts)
    const int pswz = l15 & 7;                  // P 8-block XOR

    __shared__ short Ks[4096];                 // [key][dblk^(key&7)][8]
    __shared__ short Vs[4096];                 // [d][kblk^(d&7)][8]
    __shared__ short Ps[4 * 32 * LSTR];        // per wave: rows 0-15 H, 16-31 L
    short* Pw = &Ps[wave * 32 * LSTR];

    const size_t bT = (size_t)b * T_;
    const size_t tb0 = (size_t)((b * HKV_ + kh) * 32) * 4096;
    const int qrow0H = qtH * 64 + wave * 16;   // this wave's 16 H q-rows
    const int qrow0L = qtL * 64 + wave * 16;

    // Q fragments as B-operand (same bits as A-layout load); scale folded in
    const float qscale = 0.125f * 1.44269504f;
    bf16x8 qfH[2], qfL[2];
    #pragma unroll
    for (int k0 = 0; k0 < 2; k0++) {
        const short* qpH = QKV + (bT + qrow0H + l15) * NQKV_ + h * 64;
        const short* qpL = QKV + (bT + qrow0L + l15) * NQKV_ + h * 64;
        bf16x8 rH = *(const bf16x8*)(qpH + k0 * 32 + quad * 8);
        bf16x8 rL = *(const bf16x8*)(qpL + k0 * 32 + quad * 8);
        #pragma unroll
        for (int j = 0; j < 8; j++) {
            qfH[k0][j] = f2bf(bf2f(rH[j]) * qscale);
            qfL[k0][j] = f2bf(bf2f(rL[j]) * qscale);
        }
    }

    // ALiBi bias bases at jtk=0 (S^T layout: row=key, col=q); step per tile
    const float step = slope2 * 64.f;
    f32x4 bBH[4], bBL[4];
    #pragma unroll
    for (int mtk = 0; mtk < 4; mtk++)
        #pragma unroll
        for (int r = 0; r < 4; r++) {
            const int key0 = mtk * 16 + quad * 4 + r;
            bBH[mtk][r] = slope2 * (float)(key0 - wave * 16 - l15 - qtH * 64);
            bBL[mtk][r] = slope2 * (float)(key0 - wave * 16 - l15 - qtL * 64);
        }

    const short one_s = (short)0x3F80;         // bf16 1.0
    const bf16x8 ones = {one_s, one_s, one_s, one_s, one_s, one_s, one_s, one_s};

    f32x4 OaccH[4], OaccL[4], laccH, laccL;    // O: row=q(quad*4+r), col=d
    #pragma unroll
    for (int nt = 0; nt < 4; nt++) {
        OaccH[nt] = (f32x4){0.f, 0.f, 0.f, 0.f};
        OaccL[nt] = (f32x4){0.f, 0.f, 0.f, 0.f};
    }
    laccH = (f32x4){0.f, 0.f, 0.f, 0.f};
    laccL = (f32x4){0.f, 0.f, 0.f, 0.f};

    for (int jtk = 0; jtk <= qtH; jtk++) {
        __syncthreads();                       // prev-tile consumers done
        {
            const short* Ktile = Ktg + tb0 + (size_t)jtk * 4096;
            const short* Vtile = Vtg + tb0 + (size_t)jtk * 4096;
            #pragma unroll
            for (int i = 0; i < 2; i++) {
                const int ch = wave * 2 + i;   // 1KB chunks
                gload_lds16(Ktile + ch * 512 + lane * 8, &Ks[ch * 512]);
                gload_lds16(Vtile + ch * 512 + lane * 8, &Vs[ch * 512]);
            }
        }
        __syncthreads();                       // DMA drained by barrier

        const bool doL = (jtk <= qtL);
        const float jb = step * (float)jtk;

        // K fragments (A-operand), shared by both Q-tiles
        bf16x8 kf[8];
        #pragma unroll
        for (int mtk = 0; mtk < 4; mtk++)
            #pragma unroll
            for (int k0 = 0; k0 < 2; k0++)
                kf[mtk * 2 + k0] = *(const bf16x8*)
                    &Ks[(mtk * 16 + l15) * 64 + (((k0 * 4 + quad) * 8) ^ lswz)];

        // S^T + bias -> exp2 -> packed b64 P write at row q=l15
        {
            const bool diag = (jtk == qtH);
            #pragma unroll
            for (int mtk = 0; mtk < 4; mtk++) {
                const f32x4 bias = bBH[mtk] + jb;
                f32x4 a = bias;
                a = mfma32(kf[mtk * 2 + 0], qfH[0], a);
                a = mfma32(kf[mtk * 2 + 1], qfH[1], a);
                float p[4];
                #pragma unroll
                for (int r = 0; r < 4; r++) {
                    p[r] = __builtin_amdgcn_exp2f(a[r]);
                    if (diag && bias[r] > 0.f) p[r] = 0.f;
                }
                *(bf16x4*)&Pw[l15 * LSTR
                    + ((((mtk * 2 + (quad >> 1)) ^ pswz) << 3) | ((quad & 1) << 2))]
                    = pack4_trunc(p[0], p[1], p[2], p[3]);
            }
        }
        if (doL) {
            const bool diag = (jtk == qtL);
            #pragma unroll
            for (int mtk = 0; mtk < 4; mtk++) {
                const f32x4 bias = bBL[mtk] + jb;
                f32x4 a = bias;
                a = mfma32(kf[mtk * 2 + 0], qfL[0], a);
                a = mfma32(kf[mtk * 2 + 1], qfL[1], a);
                float p[4];
                #pragma unroll
                for (int r = 0; r < 4; r++) {
                    p[r] = __builtin_amdgcn_exp2f(a[r]);
                    if (diag && bias[r] > 0.f) p[r] = 0.f;
                }
                *(bf16x4*)&Pw[(16 + l15) * LSTR
                    + ((((mtk * 2 + (quad >> 1)) ^ pswz) << 3) | ((quad & 1) << 2))]
                    = pack4_trunc(p[0], p[1], p[2], p[3]);
            }
        }
        __asm__ volatile("s_waitcnt lgkmcnt(0)" ::: "memory");

        // V fragments once; O += P @ V, l += P @ 1 (all K=32 MFMA)
        bf16x8 vf[8];
        #pragma unroll
        for (int nt = 0; nt < 4; nt++)
            #pragma unroll
            for (int k0 = 0; k0 < 2; k0++)
                vf[nt * 2 + k0] = *(const bf16x8*)
                    &Vs[(nt * 16 + l15) * 64 + (((k0 * 4 + quad) * 8) ^ lswz)];

        {
            bf16x8 pf0 = *(const bf16x8*)&Pw[l15 * LSTR + (((quad ^ pswz)) << 3)];
            bf16x8 pf1 = *(const bf16x8*)&Pw[l15 * LSTR + (((4 + quad) ^ pswz) << 3)];
            laccH = mfma32(pf0, ones, laccH);
            laccH = mfma32(pf1, ones, laccH);
            #pragma unroll
            for (int nt = 0; nt < 4; nt++) {
                OaccH[nt] = mfma32(pf0, vf[nt * 2 + 0], OaccH[nt]);
                OaccH[nt] = mfma32(pf1, vf[nt * 2 + 1], OaccH[nt]);
            }
        }
        if (doL) {
            bf16x8 pf0 = *(const bf16x8*)&Pw[(16 + l15) * LSTR + (((quad ^ pswz)) << 3)];
            bf16x8 pf1 = *(const bf16x8*)&Pw[(16 + l15) * LSTR + (((4 + quad) ^ pswz) << 3)];
            laccL = mfma32(pf0, ones, laccL);
            laccL = mfma32(pf1, ones, laccL);
            #pragma unroll
            for (int nt = 0; nt < 4; nt++) {
                OaccL[nt] = mfma32(pf0, vf[nt * 2 + 0], OaccL[nt]);
                OaccL[nt] = mfma32(pf1, vf[nt * 2 + 1], OaccL[nt]);
            }
        }
    }

    // epilogue: O row=q(quad*4+r), col=d(nt*16+l15); l = lacc[r]
    #pragma unroll
    for (int r = 0; r < 4; r++) {
        const float invH = 1.f / laccH[r];
        const float invL = 1.f / laccL[r];
        const int rowH = qrow0H + quad * 4 + r;
        const int rowL = qrow0L + quad * 4 + r;
        short* ypH = Y + (bT + rowH) * C_ + h * 64 + l15;
        short* ypL = Y + (bT + rowL) * C_ + h * 64 + l15;
        #pragma unroll
        for (int nt = 0; nt < 4; nt++) {
            ypH[nt * 16] = f2bf(OaccH[nt][r] * invH);
            ypL[nt * 16] = f2bf(OaccL[nt][r] * invL);
        }
    }
}

extern "C" void kernel_launch(void* const* d_in, const int* in_sizes, int n_in,
                              void* d_out, int out_size, void* d_ws, size_t ws_size,
                              hipStream_t stream) {
    const float* x  = (const float*)d_in[0];
    const float* Wq = (const float*)d_in[1];
    const float* Wk = (const float*)d_in[2];
    const float* Wv = (const float*)d_in[3];
    const float* Wo = (const float*)d_in[4];
    float* out = (float*)d_out;

    const int M = B_ * T_;                           // 4096
    short* xb  = (short*)d_ws;                       // [4096][1024]
    short* Wt  = xb  + (size_t)M * C_;               // [1536][1024]
    short* Wot = Wt  + (size_t)NQKV_ * C_;           // [1024][1024]
    short* QKV = Wot + (size_t)C_ * C_;              // [4096][1536] (Q cols only)
    short* Yb  = QKV + (size_t)M * NQKV_;            // [4096][1024]
    short* Ktg = Yb  + (size_t)M * C_;               // [8][32][4096] swizzled
    short* Vtg = Ktg + (size_t)8 * 32 * 4096;        // [8][32][4096] swizzled

    cast_bf16<<<dim3(M * C_ / (256 * 8)), dim3(256), 0, stream>>>(x, xb, M * C_);
    w_transpose<<<dim3(32, 32, 4), dim3(32, 8), 0, stream>>>(Wq, Wk, Wv, Wo, Wt, Wot);

    gemm_bf16<1><<<dim3(NQKV_ / 128, M / 64), dim3(256), 0, stream>>>(
        xb, Wt, QKV, Ktg, Vtg, M, NQKV_, C_);
    attn_mfma<<<dim3(NQT_ / 2, B_ * H_), dim3(256), 0, stream>>>(QKV, Ktg, Vtg, Yb);
    gemm_bf16<0><<<dim3(C_ / 128, M / 64), dim3(256), 0, stream>>>(
        Yb, Wot, out, nullptr, nullptr, M, C_, C_);
}